// Round 1
// baseline (57974.017 us; speedup 1.0000x reference)
//
#include <hip/hip_runtime.h>
#include <math.h>

#define Bsz 16
#define Tsz 1000
#define Nsz 100
#define ENC 512
#define VOCAB 10025
#define EMB 640
#define HID 1024
#define ATT 1024
#define KX (EMB + ENC)          // 1152
#define KRO (HID + EMB + ENC)   // 2176

typedef short s16x8 __attribute__((ext_vector_type(8)));
typedef unsigned short u16x4 __attribute__((ext_vector_type(4)));
typedef float f32x4 __attribute__((ext_vector_type(4)));

__device__ __forceinline__ float4 ld4(const float* p) { return *reinterpret_cast<const float4*>(p); }
__device__ __forceinline__ float dot4(float4 a, float4 b) { return a.x*b.x + a.y*b.y + a.z*b.z + a.w*b.w; }
__device__ __forceinline__ float sigmoidf_(float x) { return 1.f / (1.f + __expf(-x)); }
__device__ __forceinline__ float ftanh_(float x) {
    x = fminf(15.f, fmaxf(-15.f, x));
    float e = __expf(2.f * x);
    return (e - 1.f) / (e + 1.f);
}
__device__ __forceinline__ unsigned short f2bf(float x) {
    union { float f; unsigned u; } v; v.f = x;
    unsigned r = v.u + 0x7fffu + ((v.u >> 16) & 1u);
    return (unsigned short)(r >> 16);
}
__device__ __forceinline__ float bf2f(unsigned short h) {
    union { float f; unsigned u; } v; v.u = ((unsigned)h) << 16;
    return v.f;
}

// ---------------- init: zero accum, ctx slots of roA, barrier/denom block ----------------
__global__ __launch_bounds__(256) void k_init(float* __restrict__ accum, float* __restrict__ roA,
                                              float* __restrict__ bar) {
    int i = blockIdx.x * 256 + threadIdx.x;
    if (i < Bsz * Tsz) accum[i] = 0.f;
    if (i < Bsz * Nsz * ENC) {
        int r = i / ENC, d = i - r * ENC;
        roA[(size_t)r * KRO + HID + EMB + d] = 0.f;
    }
    if (i < 1024) bar[i] = 0.f;
}

// ---------------- shifted embedding into roA[:, HID:HID+EMB] ----------------
__global__ __launch_bounds__(256) void k_embed(const int* __restrict__ labels,
                                               const float* __restrict__ table,
                                               float* __restrict__ roA) {
    int idx = blockIdx.x * 256 + threadIdx.x;
    if (idx >= Bsz * Nsz * EMB) return;
    int e = idx % EMB;
    int bn = idx / EMB;
    int n = bn % Nsz, b = bn / Nsz;
    float v = 0.f;
    if (n > 0) {
        int lab = labels[b * Nsz + n - 1];
        v = table[(size_t)lab * EMB + e];
    }
    roA[(size_t)bn * KRO + HID + e] = v;
}

// ======== MFMA split-bf16 GEMM: C = A[M,K] @ W[Nc,K]^T + bias ========
template <int MODE>
__global__ __launch_bounds__(256) void mfma_gemm(const float* __restrict__ A,
                                                 const float* __restrict__ W,
                                                 const float* __restrict__ bias,
                                                 float* __restrict__ C,
                                                 int M, int Nc, int K, int ldC) {
    __shared__ unsigned short Ah[128][40], Al[128][40], Wh[128][40], Wl[128][40];
    int tid = threadIdx.x;
    int lane = tid & 63;
    int wave = tid >> 6;
    int wm = (wave >> 1) * 64, wn = (wave & 1) * 64;
    int m0 = blockIdx.y * 128, n0 = blockIdx.x * 128;
    int lrow = tid >> 1;
    int lcol = (tid & 1) * 16;
    bool aval = (m0 + lrow) < M;
    bool wval = (n0 + lrow) < Nc;
    const float* Arow = A + (size_t)(m0 + lrow) * K + lcol;
    const float* Wrow = W + (size_t)(n0 + lrow) * K + lcol;
    int frow = lane & 15, fk = (lane >> 4) * 8;

    f32x4 acc[4][4];
#pragma unroll
    for (int i = 0; i < 4; i++)
#pragma unroll
        for (int j = 0; j < 4; j++) acc[i][j] = (f32x4){0.f, 0.f, 0.f, 0.f};

    const float4 z4 = {0.f, 0.f, 0.f, 0.f};
    for (int k0 = 0; k0 < K; k0 += 32) {
#pragma unroll
        for (int c = 0; c < 16; c += 4) {
            float4 av = aval ? ld4(Arow + k0 + c) : z4;
            u16x4 hv, lv;
            hv.x = f2bf(av.x); lv.x = f2bf(av.x - bf2f(hv.x));
            hv.y = f2bf(av.y); lv.y = f2bf(av.y - bf2f(hv.y));
            hv.z = f2bf(av.z); lv.z = f2bf(av.z - bf2f(hv.z));
            hv.w = f2bf(av.w); lv.w = f2bf(av.w - bf2f(hv.w));
            *(u16x4*)&Ah[lrow][lcol + c] = hv;
            *(u16x4*)&Al[lrow][lcol + c] = lv;
            float4 wv = wval ? ld4(Wrow + k0 + c) : z4;
            hv.x = f2bf(wv.x); lv.x = f2bf(wv.x - bf2f(hv.x));
            hv.y = f2bf(wv.y); lv.y = f2bf(wv.y - bf2f(hv.y));
            hv.z = f2bf(wv.z); lv.z = f2bf(wv.z - bf2f(hv.z));
            hv.w = f2bf(wv.w); lv.w = f2bf(wv.w - bf2f(hv.w));
            *(u16x4*)&Wh[lrow][lcol + c] = hv;
            *(u16x4*)&Wl[lrow][lcol + c] = lv;
        }
        __syncthreads();
        s16x8 afh[4], afl[4], bfh[4], bfl[4];
#pragma unroll
        for (int i = 0; i < 4; i++) {
            afh[i] = *(const s16x8*)&Ah[wm + i * 16 + frow][fk];
            afl[i] = *(const s16x8*)&Al[wm + i * 16 + frow][fk];
            bfh[i] = *(const s16x8*)&Wh[wn + i * 16 + frow][fk];
            bfl[i] = *(const s16x8*)&Wl[wn + i * 16 + frow][fk];
        }
#pragma unroll
        for (int mi = 0; mi < 4; mi++)
#pragma unroll
            for (int ni = 0; ni < 4; ni++) {
                acc[mi][ni] = __builtin_amdgcn_mfma_f32_16x16x32_bf16(afh[mi], bfh[ni], acc[mi][ni], 0, 0, 0);
                acc[mi][ni] = __builtin_amdgcn_mfma_f32_16x16x32_bf16(afl[mi], bfh[ni], acc[mi][ni], 0, 0, 0);
                acc[mi][ni] = __builtin_amdgcn_mfma_f32_16x16x32_bf16(afh[mi], bfl[ni], acc[mi][ni], 0, 0, 0);
            }
        __syncthreads();
    }
    int crb = (lane >> 4) * 4;
    int ccol = lane & 15;
#pragma unroll
    for (int mi = 0; mi < 4; mi++) {
#pragma unroll
        for (int r = 0; r < 4; r++) {
            int m = m0 + wm + mi * 16 + crb + r;
#pragma unroll
            for (int ni = 0; ni < 4; ni++) {
                int n = n0 + wn + ni * 16 + ccol;
                if (MODE == 0) {
                    if (m < M && n < Nc) C[(size_t)m * ldC + n] = acc[mi][ni][r] + bias[n];
                } else {
                    float v = (n < Nc) ? acc[mi][ni][r] + bias[n] : -INFINITY;
                    float o = __shfl_xor(v, 1, 64);
                    if (((lane & 1) == 0) && m < M && n < Nc)
                        C[(size_t)m * ldC + (n >> 1)] = fmaxf(v, o);
                }
            }
        }
    }
}

// ---------------- inv_fertility ----------------
__global__ __launch_bounds__(256) void k_ifert(const float* __restrict__ enc,
                                               const float* __restrict__ Wfert,
                                               float* __restrict__ ifert) {
    int wv = (blockIdx.x * 256 + threadIdx.x) >> 6;
    int lane = threadIdx.x & 63;
    if (wv >= Bsz * Tsz) return;
    const float* row = enc + (size_t)wv * ENC;
    float s = 0.f;
    for (int k = lane * 4; k < ENC; k += 256) s += dot4(ld4(row + k), ld4(Wfert + k));
    for (int o = 32; o; o >>= 1) s += __shfl_xor(s, o, 64);
    if (lane == 0) ifert[wv] = 1.f / (1.f + __expf(-s));
}

// ---------------- hierarchical grid barrier (normal launch, all blocks resident) ----------------
// bm layout (uints): [0..512) 32 group counters (64B stride), [512] root, [528] generation.
// Requires gridDim.x % 32 == 0. Monotonic counters, zeroed by k_init each run.
__device__ __forceinline__ void gsync(unsigned* bm, unsigned& ep) {
    __threadfence();
    __syncthreads();
    if (threadIdx.x == 0) {
        ep++;
        unsigned gsize = gridDim.x >> 5;
        unsigned r = atomicAdd(&bm[(blockIdx.x & 31) << 4], 1u) + 1u;
        if (r == ep * gsize) {
            unsigned rr = atomicAdd(&bm[512], 1u) + 1u;
            if (rr == (ep << 5)) {
                atomicAdd(&bm[528], 1u);
            }
        }
        while (__hip_atomic_load(&bm[528], __ATOMIC_ACQUIRE, __HIP_MEMORY_SCOPE_AGENT) < ep) {
            __builtin_amdgcn_s_sleep(2);
        }
    }
    __syncthreads();
    __threadfence();
}

// ---------------- persistent decode loop: all 100 steps, 4 grid syncs per step ----------------
// Phase A: LSTM gates+cell (items j*2) + zero denom
// Phase B: s_t = h @ W_s^T (items a)
// Phase C: energies -> w = exp(e) (bounded: |e| <= sum|v_att| ~ 16.4, no max pass needed),
//          per-(b,4t) item, one denom atomicAdd per item
// Phase D: ctx = sum_t (w/denom) * enc (chunked atomics, writes NORMALIZED ctx into roA)
//          + accum[b,t] += w/denom * ifert * 0.5
__global__ __launch_bounds__(256, 4) void k_loop(
    const float* __restrict__ enc, const int* __restrict__ seqlen,
    const float* __restrict__ Wih, const float* __restrict__ Whh,
    const float* __restrict__ bih, const float* __restrict__ bhh,
    const float* __restrict__ Wsm, const float* __restrict__ Wfb,
    const float* __restrict__ vatt, const float* __restrict__ ifert,
    float* roA, float* __restrict__ cbuf, const float* __restrict__ encctx,
    float* __restrict__ accum, float* __restrict__ expw, float* __restrict__ st,
    float* __restrict__ denom, unsigned* __restrict__ bar) {
    const int tid = threadIdx.x;
    const int lane = tid & 63;
    const int wid4 = (blockIdx.x << 2) + (tid >> 6);
    const int nwv = gridDim.x << 2;
    const int gtid = blockIdx.x * 256 + tid;
    const int gth = gridDim.x * 256;
    unsigned ep = 0;

    for (int t = 0; t < Nsz; ++t) {
        // ---------------- Phase A: gates + LSTM cell ----------------
        if (gtid < Bsz) denom[gtid << 4] = 0.f;
        for (int it = wid4; it < 2 * HID; it += nwv) {
            int j = it >> 1;
            int b0 = (it & 1) << 3;
            float acc[4][8];
#pragma unroll
            for (int g = 0; g < 4; g++)
#pragma unroll
                for (int bb = 0; bb < 8; bb++) acc[g][bb] = 0.f;

            const float* wi0 = Wih + (size_t)(0 * HID + j) * KX;
            const float* wi1 = Wih + (size_t)(1 * HID + j) * KX;
            const float* wi2 = Wih + (size_t)(2 * HID + j) * KX;
            const float* wi3 = Wih + (size_t)(3 * HID + j) * KX;
            const float* xrow[8];
            const float* prow[8];
#pragma unroll
            for (int bb = 0; bb < 8; bb++) {
                xrow[bb] = roA + (size_t)((b0 + bb) * Nsz + t) * KRO;
                prow[bb] = roA + (size_t)((b0 + bb) * Nsz + (t - 1)) * KRO;
            }
            for (int k = lane * 4; k < EMB; k += 256) {
                float4 w0 = ld4(wi0 + k), w1 = ld4(wi1 + k), w2 = ld4(wi2 + k), w3 = ld4(wi3 + k);
#pragma unroll
                for (int bb = 0; bb < 8; bb++) {
                    float4 x = ld4(xrow[bb] + HID + k);
                    acc[0][bb] += dot4(w0, x); acc[1][bb] += dot4(w1, x);
                    acc[2][bb] += dot4(w2, x); acc[3][bb] += dot4(w3, x);
                }
            }
            if (t > 0) {
                for (int k = lane * 4; k < ENC; k += 256) {
                    float4 w0 = ld4(wi0 + EMB + k), w1 = ld4(wi1 + EMB + k);
                    float4 w2 = ld4(wi2 + EMB + k), w3 = ld4(wi3 + EMB + k);
#pragma unroll
                    for (int bb = 0; bb < 8; bb++) {
                        float4 x = ld4(prow[bb] + HID + EMB + k);
                        acc[0][bb] += dot4(w0, x); acc[1][bb] += dot4(w1, x);
                        acc[2][bb] += dot4(w2, x); acc[3][bb] += dot4(w3, x);
                    }
                }
                const float* wh0 = Whh + (size_t)(0 * HID + j) * HID;
                const float* wh1 = Whh + (size_t)(1 * HID + j) * HID;
                const float* wh2 = Whh + (size_t)(2 * HID + j) * HID;
                const float* wh3 = Whh + (size_t)(3 * HID + j) * HID;
                for (int k = lane * 4; k < HID; k += 256) {
                    float4 w0 = ld4(wh0 + k), w1 = ld4(wh1 + k), w2 = ld4(wh2 + k), w3 = ld4(wh3 + k);
#pragma unroll
                    for (int bb = 0; bb < 8; bb++) {
                        float4 x = ld4(prow[bb] + k);
                        acc[0][bb] += dot4(w0, x); acc[1][bb] += dot4(w1, x);
                        acc[2][bb] += dot4(w2, x); acc[3][bb] += dot4(w3, x);
                    }
                }
            }
#pragma unroll
            for (int g = 0; g < 4; g++)
#pragma unroll
                for (int bb = 0; bb < 8; bb++) {
                    float v = acc[g][bb];
                    for (int o = 32; o; o >>= 1) v += __shfl_xor(v, o, 64);
                    acc[g][bb] = v;
                }
            if (lane < 8) {
                int b = b0 + lane;
                float gi = 0.f, gf = 0.f, gg = 0.f, go = 0.f;
#pragma unroll
                for (int bb = 0; bb < 8; bb++)
                    if (lane == bb) { gi = acc[0][bb]; gf = acc[1][bb]; gg = acc[2][bb]; go = acc[3][bb]; }
                gi += bih[j] + bhh[j];
                gf += bih[HID + j] + bhh[HID + j];
                gg += bih[2 * HID + j] + bhh[2 * HID + j];
                go += bih[3 * HID + j] + bhh[3 * HID + j];
                float cold = (t > 0) ? cbuf[b * HID + j] : 0.f;
                float cn = sigmoidf_(gf) * cold + sigmoidf_(gi) * ftanh_(gg);
                float hn = sigmoidf_(go) * ftanh_(cn);
                cbuf[b * HID + j] = cn;
                roA[(size_t)(b * Nsz + t) * KRO + j] = hn;
            }
        }
        gsync(bar, ep);

        // ---------------- Phase B: s_t (one wave per attention unit a) ----------------
        for (int it = wid4; it < ATT; it += nwv) {
            float acc2[16];
#pragma unroll
            for (int b = 0; b < 16; b++) acc2[b] = 0.f;
            const float* wr = Wsm + (size_t)it * HID;
            for (int k = lane * 4; k < HID; k += 256) {
                float4 w = ld4(wr + k);
#pragma unroll
                for (int b = 0; b < 16; b++)
                    acc2[b] += dot4(w, ld4(roA + (size_t)(b * Nsz + t) * KRO + k));
            }
#pragma unroll
            for (int b = 0; b < 16; b++) {
                float v = acc2[b];
                for (int o = 32; o; o >>= 1) v += __shfl_xor(v, o, 64);
                acc2[b] = v;
            }
            if (lane < 16) {
                float v = 0.f;
#pragma unroll
                for (int b = 0; b < 16; b++)
                    if (lane == b) v = acc2[b];
                st[lane * ATT + it] = v;
            }
        }
        gsync(bar, ep);

        // ---------------- Phase C: energies -> exp weights + denominators ----------------
        for (int it = wid4; it < Bsz * 250; it += nwv) {
            int b = it / 250;
            int tt0 = (it - b * 250) << 2;
            int L = seqlen[b];
            const float* sr = st + b * ATT;
            const float* ecb = encctx + ((size_t)b * Tsz + tt0) * ATT;
            float ac0 = accum[b * Tsz + tt0 + 0];
            float ac1 = accum[b * Tsz + tt0 + 1];
            float ac2 = accum[b * Tsz + tt0 + 2];
            float ac3 = accum[b * Tsz + tt0 + 3];
            float e0 = 0.f, e1 = 0.f, e2 = 0.f, e3 = 0.f;
            for (int k = lane * 4; k < ATT; k += 256) {
                float4 s4 = ld4(sr + k), f4 = ld4(Wfb + k), v4 = ld4(vatt + k);
                float4 c0 = ld4(ecb + k);
                float4 c1 = ld4(ecb + ATT + k);
                float4 c2 = ld4(ecb + 2 * ATT + k);
                float4 c3 = ld4(ecb + 3 * ATT + k);
                e0 += ftanh_(c0.x + s4.x + ac0 * f4.x) * v4.x + ftanh_(c0.y + s4.y + ac0 * f4.y) * v4.y
                    + ftanh_(c0.z + s4.z + ac0 * f4.z) * v4.z + ftanh_(c0.w + s4.w + ac0 * f4.w) * v4.w;
                e1 += ftanh_(c1.x + s4.x + ac1 * f4.x) * v4.x + ftanh_(c1.y + s4.y + ac1 * f4.y) * v4.y
                    + ftanh_(c1.z + s4.z + ac1 * f4.z) * v4.z + ftanh_(c1.w + s4.w + ac1 * f4.w) * v4.w;
                e2 += ftanh_(c2.x + s4.x + ac2 * f4.x) * v4.x + ftanh_(c2.y + s4.y + ac2 * f4.y) * v4.y
                    + ftanh_(c2.z + s4.z + ac2 * f4.z) * v4.z + ftanh_(c2.w + s4.w + ac2 * f4.w) * v4.w;
                e3 += ftanh_(c3.x + s4.x + ac3 * f4.x) * v4.x + ftanh_(c3.y + s4.y + ac3 * f4.y) * v4.y
                    + ftanh_(c3.z + s4.z + ac3 * f4.z) * v4.z + ftanh_(c3.w + s4.w + ac3 * f4.w) * v4.w;
            }
            for (int o = 32; o; o >>= 1) {
                e0 += __shfl_xor(e0, o, 64);
                e1 += __shfl_xor(e1, o, 64);
                e2 += __shfl_xor(e2, o, 64);
                e3 += __shfl_xor(e3, o, 64);
            }
            float w0 = (tt0 + 0 < L) ? __expf(e0) : 0.f;
            float w1 = (tt0 + 1 < L) ? __expf(e1) : 0.f;
            float w2 = (tt0 + 2 < L) ? __expf(e2) : 0.f;
            float w3 = (tt0 + 3 < L) ? __expf(e3) : 0.f;
            float wsum = w0 + w1 + w2 + w3;
            if (lane == 0) {
                float4 wv; wv.x = w0; wv.y = w1; wv.z = w2; wv.w = w3;
                *reinterpret_cast<float4*>(expw + b * Tsz + tt0) = wv;
                if (wsum > 0.f) atomicAdd(&denom[b << 4], wsum);
            }
        }
        gsync(bar, ep);

        // ---------------- Phase D: context (normalized) + accum update ----------------
        for (int it = wid4; it < 1024; it += nwv) {
            int b = it >> 6;
            int ch = (it >> 1) & 31;
            int half = it & 1;
            int L = seqlen[b];
            int tt0 = ch * 32;
            int tt1 = min(tt0 + 32, L);
            if (tt0 < tt1) {
                float inv = 1.f / denom[b << 4];
                int d = (half << 8) + lane * 4;
                float s0 = 0.f, s1 = 0.f, s2 = 0.f, s3 = 0.f;
                const float* ebase = enc + (size_t)b * Tsz * ENC + d;
                const float* wrow = expw + b * Tsz;
                for (int tt = tt0; tt < tt1; ++tt) {
                    float wt = wrow[tt];
                    float4 e4 = ld4(ebase + (size_t)tt * ENC);
                    s0 += wt * e4.x; s1 += wt * e4.y; s2 += wt * e4.z; s3 += wt * e4.w;
                }
                float* dst = roA + (size_t)(b * Nsz + t) * KRO + HID + EMB + d;
                atomicAdd(dst + 0, s0 * inv);
                atomicAdd(dst + 1, s1 * inv);
                atomicAdd(dst + 2, s2 * inv);
                atomicAdd(dst + 3, s3 * inv);
            }
        }
        for (int i = gtid; i < Bsz * Tsz; i += gth) {
            int b = i / Tsz;
            accum[i] += expw[i] * ifert[i] * (0.5f / denom[b << 4]);
        }
        gsync(bar, ep);
    }
}

// ---------------- final small outputs: h, c, att_ctx, accum ----------------
__global__ __launch_bounds__(256) void k_final(const float* __restrict__ roA, const float* __restrict__ cbuf,
                                               const float* __restrict__ accum, float* __restrict__ out) {
    int idx = blockIdx.x * 256 + threadIdx.x;
    const int base = Bsz * Nsz * VOCAB;
    const int OH = Bsz * HID, OC = Bsz * HID, OA = Bsz * ENC, OAC = Bsz * Tsz;
    if (idx < OH) {
        int b = idx / HID, j = idx % HID;
        out[base + idx] = roA[(size_t)(b * Nsz + Nsz - 1) * KRO + j];
        return;
    }
    idx -= OH;
    if (idx < OC) { out[base + OH + idx] = cbuf[idx]; return; }
    idx -= OC;
    if (idx < OA) {
        int b = idx / ENC, d = idx % ENC;
        out[base + OH + OC + idx] = roA[(size_t)(b * Nsz + Nsz - 1) * KRO + HID + EMB + d];
        return;
    }
    idx -= OA;
    if (idx < OAC) out[base + OH + OC + OA + idx] = accum[idx];
}

extern "C" void kernel_launch(void* const* d_in, const int* in_sizes, int n_in,
                              void* d_out, int out_size, void* d_ws, size_t ws_size,
                              hipStream_t stream) {
    const float* enc   = (const float*)d_in[0];
    const int* labels  = (const int*)d_in[1];
    const int* seqlen  = (const int*)d_in[2];
    const float* table = (const float*)d_in[3];
    const float* Wih   = (const float*)d_in[4];
    const float* Whh   = (const float*)d_in[5];
    const float* bih   = (const float*)d_in[6];
    const float* bhh   = (const float*)d_in[7];
    const float* Wsm   = (const float*)d_in[8];
    const float* Wenc  = (const float*)d_in[9];
    const float* benc  = (const float*)d_in[10];
    const float* vatt  = (const float*)d_in[11];
    const float* Wfert = (const float*)d_in[12];
    const float* Wfb   = (const float*)d_in[13];
    const float* Wro   = (const float*)d_in[14];
    const float* bro   = (const float*)d_in[15];
    const float* Wout  = (const float*)d_in[16];
    const float* bout  = (const float*)d_in[17];
    float* out = (float*)d_out;

    // workspace layout (floats); same as before (~83 MB). Barrier/denom block
    // aliases the FRONT of rmx (rmx only used after the persistent loop).
    float* ws = (float*)d_ws;
    float* roA    = ws;                              // [B*N][KRO]
    float* cbuf   = roA + (size_t)1600 * KRO;        // B*HID
    float* encctx = cbuf + Bsz * HID;                // [B*T][ATT]
    float* ifert  = encctx + (size_t)Bsz * Tsz * ATT;
    float* accum  = ifert + Bsz * Tsz;
    float* enw    = accum + Bsz * Tsz;               // exp-weights
    float* st     = enw + Bsz * Tsz;
    float* rmx    = st + Bsz * ATT;                  // [B*N][512]
    float* denomF = rmx;                             // 16 padded denominators (16 floats apart)
    unsigned* barU = (unsigned*)(rmx + 256);         // barrier counters (rmx[256..1024))

    k_init<<<3200, 256, 0, stream>>>(accum, roA, rmx);
    k_embed<<<(Bsz * Nsz * EMB + 255) / 256, 256, 0, stream>>>(labels, table, roA);
    mfma_gemm<0><<<dim3(ATT / 128, (Bsz * Tsz) / 128), 256, 0, stream>>>(enc, Wenc, benc, encctx,
                                                                        Bsz * Tsz, ATT, ENC, ATT);
    k_ifert<<<(Bsz * Tsz * 64 + 255) / 256, 256, 0, stream>>>(enc, Wfert, ifert);

    // persistent decode loop: grid clamped to guaranteed co-residency
    static int s_nblk = 0;
    if (s_nblk == 0) {
        int occ = 0;
        if (hipOccupancyMaxActiveBlocksPerMultiprocessor(&occ, k_loop, 256, 0) != hipSuccess || occ < 1)
            occ = 1;  // 256-thread, 0-LDS block always fits at least once per CU
        long cap = (long)occ * 256;   // 256 CUs on MI355X
        s_nblk = (int)(cap < 1024 ? cap : 1024);
        s_nblk &= ~31;                // barrier requires multiple of 32
        if (s_nblk < 32) s_nblk = 32;
    }
    k_loop<<<s_nblk, 256, 0, stream>>>(enc, seqlen, Wih, Whh, bih, bhh, Wsm, Wfb, vatt,
                                       ifert, roA, cbuf, encctx, accum, enw, st, denomF, barU);

    // readout: [1600,2176]@[2176,1024] + bias -> maxout -> rmx [1600,512]
    mfma_gemm<1><<<dim3(1024 / 128, (1600 + 127) / 128), 256, 0, stream>>>(roA, Wro, bro, rmx,
                                                                          1600, 1024, KRO, 512);
    // logits: [1600,512]@[512,10025] + bias -> d_out
    mfma_gemm<0><<<dim3((VOCAB + 127) / 128, (1600 + 127) / 128), 256, 0, stream>>>(rmx, Wout, bout, out,
                                                                                   1600, VOCAB, 512, VOCAB);
    k_final<<<(Bsz * HID * 2 + Bsz * ENC + Bsz * Tsz + 255) / 256, 256, 0, stream>>>(roA, cbuf, accum, out);
}

// Round 4
// 22035.774 us; speedup vs baseline: 2.6309x; 2.6309x over previous
//
#include <hip/hip_runtime.h>
#include <math.h>

#define Bsz 16
#define Tsz 1000
#define Nsz 100
#define ENC 512
#define VOCAB 10025
#define EMB 640
#define HID 1024
#define ATT 1024
#define KX (EMB + ENC)          // 1152
#define KRO (HID + EMB + ENC)   // 2176

typedef short s16x8 __attribute__((ext_vector_type(8)));
typedef unsigned short u16x4 __attribute__((ext_vector_type(4)));
typedef float f32x4 __attribute__((ext_vector_type(4)));

__device__ __forceinline__ float4 ld4(const float* p) { return *reinterpret_cast<const float4*>(p); }
__device__ __forceinline__ float dot4(float4 a, float4 b) { return a.x*b.x + a.y*b.y + a.z*b.z + a.w*b.w; }
__device__ __forceinline__ float sigmoidf_(float x) { return 1.f / (1.f + __expf(-x)); }
__device__ __forceinline__ float ftanh_(float x) {
    x = fminf(15.f, fmaxf(-15.f, x));
    float e = __expf(2.f * x);
    return (e - 1.f) / (e + 1.f);
}
__device__ __forceinline__ unsigned short f2bf(float x) {
    union { float f; unsigned u; } v; v.f = x;
    unsigned r = v.u + 0x7fffu + ((v.u >> 16) & 1u);
    return (unsigned short)(r >> 16);
}
__device__ __forceinline__ float bf2f(unsigned short h) {
    union { float f; unsigned u; } v; v.u = ((unsigned)h) << 16;
    return v.f;
}

// ---------------- init: zero accum, ctx slots of roA, barrier/denom block ----------------
__global__ __launch_bounds__(256) void k_init(float* __restrict__ accum, float* __restrict__ roA,
                                              float* __restrict__ bar) {
    int i = blockIdx.x * 256 + threadIdx.x;
    if (i < Bsz * Tsz) accum[i] = 0.f;
    if (i < Bsz * Nsz * ENC) {
        int r = i / ENC, d = i - r * ENC;
        roA[(size_t)r * KRO + HID + EMB + d] = 0.f;
    }
    if (i < 2048) bar[i] = 0.f;
}

// ---------------- shifted embedding into roA[:, HID:HID+EMB] ----------------
__global__ __launch_bounds__(256) void k_embed(const int* __restrict__ labels,
                                               const float* __restrict__ table,
                                               float* __restrict__ roA) {
    int idx = blockIdx.x * 256 + threadIdx.x;
    if (idx >= Bsz * Nsz * EMB) return;
    int e = idx % EMB;
    int bn = idx / EMB;
    int n = bn % Nsz, b = bn / Nsz;
    float v = 0.f;
    if (n > 0) {
        int lab = labels[b * Nsz + n - 1];
        v = table[(size_t)lab * EMB + e];
    }
    roA[(size_t)bn * KRO + HID + e] = v;
}

// ======== MFMA split-bf16 GEMM: C = A[M,K] @ W[Nc,K]^T + bias ========
template <int MODE>
__global__ __launch_bounds__(256) void mfma_gemm(const float* __restrict__ A,
                                                 const float* __restrict__ W,
                                                 const float* __restrict__ bias,
                                                 float* __restrict__ C,
                                                 int M, int Nc, int K, int ldC) {
    __shared__ unsigned short Ah[128][40], Al[128][40], Wh[128][40], Wl[128][40];
    int tid = threadIdx.x;
    int lane = tid & 63;
    int wave = tid >> 6;
    int wm = (wave >> 1) * 64, wn = (wave & 1) * 64;
    int m0 = blockIdx.y * 128, n0 = blockIdx.x * 128;
    int lrow = tid >> 1;
    int lcol = (tid & 1) * 16;
    bool aval = (m0 + lrow) < M;
    bool wval = (n0 + lrow) < Nc;
    const float* Arow = A + (size_t)(m0 + lrow) * K + lcol;
    const float* Wrow = W + (size_t)(n0 + lrow) * K + lcol;
    int frow = lane & 15, fk = (lane >> 4) * 8;

    f32x4 acc[4][4];
#pragma unroll
    for (int i = 0; i < 4; i++)
#pragma unroll
        for (int j = 0; j < 4; j++) acc[i][j] = (f32x4){0.f, 0.f, 0.f, 0.f};

    const float4 z4 = {0.f, 0.f, 0.f, 0.f};
    for (int k0 = 0; k0 < K; k0 += 32) {
#pragma unroll
        for (int c = 0; c < 16; c += 4) {
            float4 av = aval ? ld4(Arow + k0 + c) : z4;
            u16x4 hv, lv;
            hv.x = f2bf(av.x); lv.x = f2bf(av.x - bf2f(hv.x));
            hv.y = f2bf(av.y); lv.y = f2bf(av.y - bf2f(hv.y));
            hv.z = f2bf(av.z); lv.z = f2bf(av.z - bf2f(hv.z));
            hv.w = f2bf(av.w); lv.w = f2bf(av.w - bf2f(hv.w));
            *(u16x4*)&Ah[lrow][lcol + c] = hv;
            *(u16x4*)&Al[lrow][lcol + c] = lv;
            float4 wv = wval ? ld4(Wrow + k0 + c) : z4;
            hv.x = f2bf(wv.x); lv.x = f2bf(wv.x - bf2f(hv.x));
            hv.y = f2bf(wv.y); lv.y = f2bf(wv.y - bf2f(hv.y));
            hv.z = f2bf(wv.z); lv.z = f2bf(wv.z - bf2f(hv.z));
            hv.w = f2bf(wv.w); lv.w = f2bf(wv.w - bf2f(hv.w));
            *(u16x4*)&Wh[lrow][lcol + c] = hv;
            *(u16x4*)&Wl[lrow][lcol + c] = lv;
        }
        __syncthreads();
        s16x8 afh[4], afl[4], bfh[4], bfl[4];
#pragma unroll
        for (int i = 0; i < 4; i++) {
            afh[i] = *(const s16x8*)&Ah[wm + i * 16 + frow][fk];
            afl[i] = *(const s16x8*)&Al[wm + i * 16 + frow][fk];
            bfh[i] = *(const s16x8*)&Wh[wn + i * 16 + frow][fk];
            bfl[i] = *(const s16x8*)&Wl[wn + i * 16 + frow][fk];
        }
#pragma unroll
        for (int mi = 0; mi < 4; mi++)
#pragma unroll
            for (int ni = 0; ni < 4; ni++) {
                acc[mi][ni] = __builtin_amdgcn_mfma_f32_16x16x32_bf16(afh[mi], bfh[ni], acc[mi][ni], 0, 0, 0);
                acc[mi][ni] = __builtin_amdgcn_mfma_f32_16x16x32_bf16(afl[mi], bfh[ni], acc[mi][ni], 0, 0, 0);
                acc[mi][ni] = __builtin_amdgcn_mfma_f32_16x16x32_bf16(afh[mi], bfl[ni], acc[mi][ni], 0, 0, 0);
            }
        __syncthreads();
    }
    int crb = (lane >> 4) * 4;
    int ccol = lane & 15;
#pragma unroll
    for (int mi = 0; mi < 4; mi++) {
#pragma unroll
        for (int r = 0; r < 4; r++) {
            int m = m0 + wm + mi * 16 + crb + r;
#pragma unroll
            for (int ni = 0; ni < 4; ni++) {
                int n = n0 + wn + ni * 16 + ccol;
                if (MODE == 0) {
                    if (m < M && n < Nc) C[(size_t)m * ldC + n] = acc[mi][ni][r] + bias[n];
                } else {
                    float v = (n < Nc) ? acc[mi][ni][r] + bias[n] : -INFINITY;
                    float o = __shfl_xor(v, 1, 64);
                    if (((lane & 1) == 0) && m < M && n < Nc)
                        C[(size_t)m * ldC + (n >> 1)] = fmaxf(v, o);
                }
            }
        }
    }
}

// ---------------- inv_fertility ----------------
__global__ __launch_bounds__(256) void k_ifert(const float* __restrict__ enc,
                                               const float* __restrict__ Wfert,
                                               float* __restrict__ ifert) {
    int wv = (blockIdx.x * 256 + threadIdx.x) >> 6;
    int lane = threadIdx.x & 63;
    if (wv >= Bsz * Tsz) return;
    const float* row = enc + (size_t)wv * ENC;
    float s = 0.f;
    for (int k = lane * 4; k < ENC; k += 256) s += dot4(ld4(row + k), ld4(Wfert + k));
    for (int o = 32; o; o >>= 1) s += __shfl_xor(s, o, 64);
    if (lane == 0) ifert[wv] = 1.f / (1.f + __expf(-s));
}

// ---------------- grid barrier: release/acquire fences, relaxed spin (no per-poll inv) --------
// bar layout (uints): [0..512) 32 group counters (stride 16), [512] root, [528] generation.
// Requires gridDim.x % 32 == 0. Monotonic counters, zeroed by k_init.
// Release: __threadfence() (vmcnt drain + L2 writeback) BEFORE arrival -> all plain stores
// visible at LLC before the counter bump. Acquire: __threadfence() AFTER the spin exits
// (L2/L1 invalidate) -> subsequent plain loads fetch fresh LLC data. The spin itself uses a
// RELAXED agent load: no cache maintenance per poll (R1's 352us/barrier bug).
__device__ __forceinline__ void gsync(unsigned* bm, unsigned& ep) {
    __threadfence();   // release (per wave)
    __syncthreads();
    if (threadIdx.x == 0) {
        ep++;
        unsigned gsize = gridDim.x >> 5;
        unsigned r = __hip_atomic_fetch_add(&bm[(blockIdx.x & 31) << 4], 1u,
                                            __ATOMIC_RELAXED, __HIP_MEMORY_SCOPE_AGENT) + 1u;
        if (r == ep * gsize) {
            unsigned rr = __hip_atomic_fetch_add(&bm[512], 1u,
                                                 __ATOMIC_RELAXED, __HIP_MEMORY_SCOPE_AGENT) + 1u;
            if (rr == (ep << 5))
                __hip_atomic_fetch_add(&bm[528], 1u, __ATOMIC_RELAXED, __HIP_MEMORY_SCOPE_AGENT);
        }
        while (__hip_atomic_load(&bm[528], __ATOMIC_RELAXED, __HIP_MEMORY_SCOPE_AGENT) < ep)
            __builtin_amdgcn_s_sleep(8);
    }
    __syncthreads();
    __threadfence();   // acquire (per wave)
}

// ---------------- persistent decode loop (R1 dataflow + fenced barrier) ----------------
// ALL cross-block data uses PLAIN loads/stores; visibility is provided by the gsync fences.
// Phase A: LSTM gates+cell -> h into hbuf[t&1] + roA; zero denom slot for this step
// Phase B: s_t = h @ Ws^T -> st
// Phase C: energies (reading global accum) -> expw = exp(e) (|e| <~ sum|v_att| ~16, safe),
//          atomicAdd per-item sums into denom[b*16]
// Phase D: ctx = sum_t (expw/denom) * enc via atomics into roA; accum[i] += expw*ifert*0.5/denom
__global__ __launch_bounds__(256) void k_loop(
    const float* __restrict__ enc, const int* __restrict__ seqlen,
    const float* __restrict__ Wih, const float* __restrict__ Whh,
    const float* __restrict__ bih, const float* __restrict__ bhh,
    const float* __restrict__ Wsm, const float* __restrict__ Wfb,
    const float* __restrict__ vatt, const float* __restrict__ ifert,
    float* roA, float* __restrict__ cbuf, const float* __restrict__ encctx,
    float* __restrict__ accum, float* __restrict__ expw, float* __restrict__ st,
    float* __restrict__ denom, float* __restrict__ hbuf, unsigned* __restrict__ bar) {
    const int tid = threadIdx.x;
    const int lane = tid & 63;
    const int wid4 = (blockIdx.x << 2) + (tid >> 6);
    const int nwv = gridDim.x << 2;
    const int gtid = blockIdx.x * 256 + tid;
    const int gth = gridDim.x * 256;
    unsigned ep = 0;

    for (int t = 0; t < Nsz; ++t) {
        const int cur = t & 1, prev = cur ^ 1;
        float* hcur = hbuf + cur * (Bsz * HID);
        const float* hprev = hbuf + prev * (Bsz * HID);

        // ---------------- Phase A: gates + LSTM cell ----------------
        for (int it = wid4; it < 2 * HID; it += nwv) {
            int j = it >> 1;
            int b0 = (it & 1) << 3;
            float acc[4][8];
#pragma unroll
            for (int g = 0; g < 4; g++)
#pragma unroll
                for (int bb = 0; bb < 8; bb++) acc[g][bb] = 0.f;

            const float* wi0 = Wih + (size_t)(0 * HID + j) * KX;
            const float* wi1 = Wih + (size_t)(1 * HID + j) * KX;
            const float* wi2 = Wih + (size_t)(2 * HID + j) * KX;
            const float* wi3 = Wih + (size_t)(3 * HID + j) * KX;
            for (int k = lane * 4; k < EMB; k += 256) {
                float4 w0 = ld4(wi0 + k), w1 = ld4(wi1 + k), w2 = ld4(wi2 + k), w3 = ld4(wi3 + k);
#pragma unroll
                for (int bb = 0; bb < 8; bb++) {
                    float4 x = ld4(roA + (size_t)((b0 + bb) * Nsz + t) * KRO + HID + k);
                    acc[0][bb] += dot4(w0, x); acc[1][bb] += dot4(w1, x);
                    acc[2][bb] += dot4(w2, x); acc[3][bb] += dot4(w3, x);
                }
            }
            if (t > 0) {
                for (int k = lane * 4; k < ENC; k += 256) {
                    float4 w0 = ld4(wi0 + EMB + k), w1 = ld4(wi1 + EMB + k);
                    float4 w2 = ld4(wi2 + EMB + k), w3 = ld4(wi3 + EMB + k);
#pragma unroll
                    for (int bb = 0; bb < 8; bb++) {
                        float4 x = ld4(roA + (size_t)((b0 + bb) * Nsz + (t - 1)) * KRO + HID + EMB + k);
                        acc[0][bb] += dot4(w0, x); acc[1][bb] += dot4(w1, x);
                        acc[2][bb] += dot4(w2, x); acc[3][bb] += dot4(w3, x);
                    }
                }
                const float* wh0 = Whh + (size_t)(0 * HID + j) * HID;
                const float* wh1 = Whh + (size_t)(1 * HID + j) * HID;
                const float* wh2 = Whh + (size_t)(2 * HID + j) * HID;
                const float* wh3 = Whh + (size_t)(3 * HID + j) * HID;
                for (int k = lane * 4; k < HID; k += 256) {
                    float4 w0 = ld4(wh0 + k), w1 = ld4(wh1 + k), w2 = ld4(wh2 + k), w3 = ld4(wh3 + k);
#pragma unroll
                    for (int bb = 0; bb < 8; bb++) {
                        float4 x = ld4(hprev + (b0 + bb) * HID + k);
                        acc[0][bb] += dot4(w0, x); acc[1][bb] += dot4(w1, x);
                        acc[2][bb] += dot4(w2, x); acc[3][bb] += dot4(w3, x);
                    }
                }
            }
#pragma unroll
            for (int g = 0; g < 4; g++)
#pragma unroll
                for (int bb = 0; bb < 8; bb++) {
                    float v = acc[g][bb];
                    for (int o = 32; o; o >>= 1) v += __shfl_xor(v, o, 64);
                    acc[g][bb] = v;
                }
            if (lane < 8) {
                int b = b0 + lane;
                float gi = 0.f, gf = 0.f, gg = 0.f, go = 0.f;
#pragma unroll
                for (int bb = 0; bb < 8; bb++)
                    if (lane == bb) { gi = acc[0][bb]; gf = acc[1][bb]; gg = acc[2][bb]; go = acc[3][bb]; }
                gi += bih[j] + bhh[j];
                gf += bih[HID + j] + bhh[HID + j];
                gg += bih[2 * HID + j] + bhh[2 * HID + j];
                go += bih[3 * HID + j] + bhh[3 * HID + j];
                float cold = (t > 0) ? cbuf[b * HID + j] : 0.f;
                float cn = sigmoidf_(gf) * cold + sigmoidf_(gi) * ftanh_(gg);
                float hn = sigmoidf_(go) * ftanh_(cn);
                cbuf[b * HID + j] = cn;
                roA[(size_t)(b * Nsz + t) * KRO + j] = hn;   // read post-loop by GEMM
                hcur[b * HID + j] = hn;                      // read by B / next A
            }
        }
        if (gtid < Bsz) denom[gtid * 16] = 0.f;              // this step's denom slot
        gsync(bar, ep);

        // ---------------- Phase B: s_t, one wave per (b, 16-unit group) ----------------
        for (int it = wid4; it < 1024; it += nwv) {
            int b = it >> 6, agrp = it & 63;
            const float* hb = hcur + b * HID + lane * 4;
            float4 h0 = ld4(hb), h1 = ld4(hb + 256), h2 = ld4(hb + 512), h3 = ld4(hb + 768);
            float acc2[16];
#pragma unroll
            for (int ai = 0; ai < 16; ai++) {
                const float* wr = Wsm + (size_t)(agrp * 16 + ai) * HID + lane * 4;
                acc2[ai] = dot4(h0, ld4(wr)) + dot4(h1, ld4(wr + 256))
                         + dot4(h2, ld4(wr + 512)) + dot4(h3, ld4(wr + 768));
            }
#pragma unroll
            for (int ai = 0; ai < 16; ai++) {
                float v = acc2[ai];
                for (int o = 32; o; o >>= 1) v += __shfl_xor(v, o, 64);
                acc2[ai] = v;
            }
            if (lane < 16) {
                float v = 0.f;
#pragma unroll
                for (int ai = 0; ai < 16; ai++)
                    if (lane == ai) v = acc2[ai];
                st[b * ATT + agrp * 16 + lane] = v;
            }
        }
        gsync(bar, ep);

        // ---------------- Phase C: energies -> exp weights + denominators ----------------
        for (int it = wid4; it < Bsz * 250; it += nwv) {
            int b = it / 250;
            int tt0 = (it - b * 250) << 2;
            int L = seqlen[b];
            float w0 = 0.f, w1 = 0.f, w2 = 0.f, w3 = 0.f;
            if (tt0 < L) {
                const float* sr = st + b * ATT;
                const float* ecb = encctx + ((size_t)b * Tsz + tt0) * ATT;
                float ac0 = accum[b * Tsz + tt0 + 0];
                float ac1 = accum[b * Tsz + tt0 + 1];
                float ac2 = accum[b * Tsz + tt0 + 2];
                float ac3 = accum[b * Tsz + tt0 + 3];
                float e0 = 0.f, e1 = 0.f, e2 = 0.f, e3 = 0.f;
                for (int k = lane * 4; k < ATT; k += 256) {
                    float4 s4 = ld4(sr + k);
                    float4 f4 = ld4(Wfb + k), v4 = ld4(vatt + k);
                    float4 c0 = ld4(ecb + k);
                    float4 c1 = ld4(ecb + ATT + k);
                    float4 c2 = ld4(ecb + 2 * ATT + k);
                    float4 c3 = ld4(ecb + 3 * ATT + k);
                    e0 += ftanh_(c0.x + s4.x + ac0 * f4.x) * v4.x + ftanh_(c0.y + s4.y + ac0 * f4.y) * v4.y
                        + ftanh_(c0.z + s4.z + ac0 * f4.z) * v4.z + ftanh_(c0.w + s4.w + ac0 * f4.w) * v4.w;
                    e1 += ftanh_(c1.x + s4.x + ac1 * f4.x) * v4.x + ftanh_(c1.y + s4.y + ac1 * f4.y) * v4.y
                        + ftanh_(c1.z + s4.z + ac1 * f4.z) * v4.z + ftanh_(c1.w + s4.w + ac1 * f4.w) * v4.w;
                    e2 += ftanh_(c2.x + s4.x + ac2 * f4.x) * v4.x + ftanh_(c2.y + s4.y + ac2 * f4.y) * v4.y
                        + ftanh_(c2.z + s4.z + ac2 * f4.z) * v4.z + ftanh_(c2.w + s4.w + ac2 * f4.w) * v4.w;
                    e3 += ftanh_(c3.x + s4.x + ac3 * f4.x) * v4.x + ftanh_(c3.y + s4.y + ac3 * f4.y) * v4.y
                        + ftanh_(c3.z + s4.z + ac3 * f4.z) * v4.z + ftanh_(c3.w + s4.w + ac3 * f4.w) * v4.w;
                }
                for (int o = 32; o; o >>= 1) {
                    e0 += __shfl_xor(e0, o, 64);
                    e1 += __shfl_xor(e1, o, 64);
                    e2 += __shfl_xor(e2, o, 64);
                    e3 += __shfl_xor(e3, o, 64);
                }
                w0 = __expf(e0);
                w1 = (tt0 + 1 < L) ? __expf(e1) : 0.f;
                w2 = (tt0 + 2 < L) ? __expf(e2) : 0.f;
                w3 = (tt0 + 3 < L) ? __expf(e3) : 0.f;
            }
            if (lane == 0) {
                float4 wv; wv.x = w0; wv.y = w1; wv.z = w2; wv.w = w3;
                *reinterpret_cast<float4*>(expw + b * Tsz + tt0) = wv;
                float wsum = w0 + w1 + w2 + w3;
                if (wsum > 0.f) atomicAdd(&denom[b * 16], wsum);
            }
        }
        gsync(bar, ep);

        // ---------------- Phase D: context + accum update ----------------
        for (int it = wid4; it < 1024; it += nwv) {
            int b = it >> 6;
            int ch = (it >> 1) & 31;
            int half = it & 1;
            int L = seqlen[b];
            int tt0 = ch * 32;
            int tt1 = min(tt0 + 32, L);
            if (tt0 < tt1) {
                float inv = 1.f / denom[b * 16];
                int d = (half << 8) + lane * 4;
                const float* ebase = enc + (size_t)b * Tsz * ENC + d;
                const float* wrow = expw + b * Tsz;
                float s0 = 0.f, s1 = 0.f, s2 = 0.f, s3 = 0.f;
                for (int tt = tt0; tt < tt1; ++tt) {
                    float wt = wrow[tt];
                    float4 e4 = ld4(ebase + (size_t)tt * ENC);
                    s0 += wt * e4.x; s1 += wt * e4.y; s2 += wt * e4.z; s3 += wt * e4.w;
                }
                float* dst = roA + (size_t)(b * Nsz + t) * KRO + HID + EMB + d;
                atomicAdd(dst + 0, s0 * inv);
                atomicAdd(dst + 1, s1 * inv);
                atomicAdd(dst + 2, s2 * inv);
                atomicAdd(dst + 3, s3 * inv);
            }
        }
        for (int i = gtid; i < Bsz * Tsz; i += gth) {
            int b = i / Tsz;
            accum[i] += expw[i] * ifert[i] * (0.5f / denom[b * 16]);
        }
        gsync(bar, ep);
    }
}

// ---------------- final small outputs: h, c, att_ctx, accum ----------------
__global__ __launch_bounds__(256) void k_final(const float* __restrict__ roA, const float* __restrict__ cbuf,
                                               const float* __restrict__ accum, float* __restrict__ out) {
    int idx = blockIdx.x * 256 + threadIdx.x;
    const int base = Bsz * Nsz * VOCAB;
    const int OH = Bsz * HID, OC = Bsz * HID, OA = Bsz * ENC, OAC = Bsz * Tsz;
    if (idx < OH) {
        int b = idx / HID, j = idx % HID;
        out[base + idx] = roA[(size_t)(b * Nsz + Nsz - 1) * KRO + j];
        return;
    }
    idx -= OH;
    if (idx < OC) { out[base + OH + idx] = cbuf[idx]; return; }
    idx -= OC;
    if (idx < OA) {
        int b = idx / ENC, d = idx % ENC;
        out[base + OH + OC + idx] = roA[(size_t)(b * Nsz + Nsz - 1) * KRO + HID + EMB + d];
        return;
    }
    idx -= OA;
    if (idx < OAC) out[base + OH + OC + OA + idx] = accum[idx];
}

extern "C" void kernel_launch(void* const* d_in, const int* in_sizes, int n_in,
                              void* d_out, int out_size, void* d_ws, size_t ws_size,
                              hipStream_t stream) {
    const float* enc   = (const float*)d_in[0];
    const int* labels  = (const int*)d_in[1];
    const int* seqlen  = (const int*)d_in[2];
    const float* table = (const float*)d_in[3];
    const float* Wih   = (const float*)d_in[4];
    const float* Whh   = (const float*)d_in[5];
    const float* bih   = (const float*)d_in[6];
    const float* bhh   = (const float*)d_in[7];
    const float* Wsm   = (const float*)d_in[8];
    const float* Wenc  = (const float*)d_in[9];
    const float* benc  = (const float*)d_in[10];
    const float* vatt  = (const float*)d_in[11];
    const float* Wfert = (const float*)d_in[12];
    const float* Wfb   = (const float*)d_in[13];
    const float* Wro   = (const float*)d_in[14];
    const float* bro   = (const float*)d_in[15];
    const float* Wout  = (const float*)d_in[16];
    const float* bout  = (const float*)d_in[17];
    float* out = (float*)d_out;

    // workspace layout (floats); ~83 MB. denom/bar/hbuf alias the FRONT of rmx
    // (rmx only written by the post-loop readout GEMM).
    float* ws = (float*)d_ws;
    float* roA    = ws;                              // [B*N][KRO]
    float* cbuf   = roA + (size_t)1600 * KRO;        // B*HID
    float* encctx = cbuf + Bsz * HID;                // [B*T][ATT]
    float* ifert  = encctx + (size_t)Bsz * Tsz * ATT;
    float* accum  = ifert + Bsz * Tsz;
    float* enw    = accum + Bsz * Tsz;               // exp-weights
    float* st     = enw + Bsz * Tsz;
    float* rmx    = st + Bsz * ATT;                  // [B*N][512]
    float* denomF = rmx;                             // [b*16], one slot per batch
    unsigned* barU = (unsigned*)(rmx + 512);         // barrier counters
    float* hbuf   = rmx + 2048;                      // [2][B*HID]

    k_init<<<3200, 256, 0, stream>>>(accum, roA, rmx);
    k_embed<<<(Bsz * Nsz * EMB + 255) / 256, 256, 0, stream>>>(labels, table, roA);
    mfma_gemm<0><<<dim3(ATT / 128, (Bsz * Tsz) / 128), 256, 0, stream>>>(enc, Wenc, benc, encctx,
                                                                        Bsz * Tsz, ATT, ENC, ATT);
    k_ifert<<<(Bsz * Tsz * 64 + 255) / 256, 256, 0, stream>>>(enc, Wfert, ifert);

    // persistent decode loop: grid clamped to guaranteed co-residency
    static int s_nblk = 0;
    if (s_nblk == 0) {
        int occ = 0;
        if (hipOccupancyMaxActiveBlocksPerMultiprocessor(&occ, k_loop, 256, 0) != hipSuccess || occ < 1)
            occ = 1;
        long cap = (long)occ * 256;   // 256 CUs on MI355X
        s_nblk = (int)(cap < 1024 ? cap : 1024);
        s_nblk &= ~31;                // barrier requires multiple of 32
        if (s_nblk < 32) s_nblk = 32;
    }
    k_loop<<<s_nblk, 256, 0, stream>>>(enc, seqlen, Wih, Whh, bih, bhh, Wsm, Wfb, vatt,
                                       ifert, roA, cbuf, encctx, accum, enw, st, denomF, hbuf, barU);

    // readout: [1600,2176]@[2176,1024] + bias -> maxout -> rmx [1600,512]
    mfma_gemm<1><<<dim3(1024 / 128, (1600 + 127) / 128), 256, 0, stream>>>(roA, Wro, bro, rmx,
                                                                          1600, 1024, KRO, 512);
    // logits: [1600,512]@[512,10025] + bias -> d_out
    mfma_gemm<0><<<dim3((VOCAB + 127) / 128, (1600 + 127) / 128), 256, 0, stream>>>(rmx, Wout, bout, out,
                                                                                   1600, VOCAB, 512, VOCAB);
    k_final<<<(Bsz * HID * 2 + Bsz * ENC + Bsz * Tsz + 255) / 256, 256, 0, stream>>>(roA, cbuf, accum, out);
}

// Round 5
// 9636.575 us; speedup vs baseline: 6.0160x; 2.2867x over previous
//
#include <hip/hip_runtime.h>
#include <math.h>

#define Bsz 16
#define Tsz 1000
#define Nsz 100
#define ENC 512
#define VOCAB 10025
#define EMB 640
#define HID 1024
#define ATT 1024
#define KX (EMB + ENC)          // 1152
#define KRO (HID + EMB + ENC)   // 2176

typedef short s16x8 __attribute__((ext_vector_type(8)));
typedef unsigned short u16x4 __attribute__((ext_vector_type(4)));
typedef float f32x4 __attribute__((ext_vector_type(4)));

__device__ __forceinline__ float4 ld4(const float* p) { return *reinterpret_cast<const float4*>(p); }
__device__ __forceinline__ float dot4(float4 a, float4 b) { return a.x*b.x + a.y*b.y + a.z*b.z + a.w*b.w; }
__device__ __forceinline__ float sigmoidf_(float x) { return 1.f / (1.f + __expf(-x)); }
__device__ __forceinline__ float ftanh_(float x) {
    x = fminf(15.f, fmaxf(-15.f, x));
    float e = __expf(2.f * x);
    return (e - 1.f) / (e + 1.f);
}
__device__ __forceinline__ unsigned short f2bf(float x) {
    union { float f; unsigned u; } v; v.f = x;
    unsigned r = v.u + 0x7fffu + ((v.u >> 16) & 1u);
    return (unsigned short)(r >> 16);
}
__device__ __forceinline__ float bf2f(unsigned short h) {
    union { float f; unsigned u; } v; v.u = ((unsigned)h) << 16;
    return v.f;
}

// -------- LLC-coherent access for mutable cross-block data (no L1/L2 involvement) --------
__device__ __forceinline__ float ldcg(const float* p) {
    return __hip_atomic_load((const float*)p, __ATOMIC_RELAXED, __HIP_MEMORY_SCOPE_AGENT);
}
__device__ __forceinline__ void stcg(float* p, float v) {
    __hip_atomic_store(p, v, __ATOMIC_RELAXED, __HIP_MEMORY_SCOPE_AGENT);
}
__device__ __forceinline__ float4 ld4cg(const float* p) {
    float4 r; r.x = ldcg(p); r.y = ldcg(p + 1); r.z = ldcg(p + 2); r.w = ldcg(p + 3); return r;
}

// ---------------- init: zero accum, ctx slots of roA, barrier/denom block ----------------
__global__ __launch_bounds__(256) void k_init(float* __restrict__ accum, float* __restrict__ roA,
                                              float* __restrict__ bar) {
    int i = blockIdx.x * 256 + threadIdx.x;
    if (i < Bsz * Tsz) accum[i] = 0.f;
    if (i < Bsz * Nsz * ENC) {
        int r = i / ENC, d = i - r * ENC;
        roA[(size_t)r * KRO + HID + EMB + d] = 0.f;
    }
    if (i < 4096) bar[i] = 0.f;
}

// ---------------- shifted embedding into roA[:, HID:HID+EMB] ----------------
__global__ __launch_bounds__(256) void k_embed(const int* __restrict__ labels,
                                               const float* __restrict__ table,
                                               float* __restrict__ roA) {
    int idx = blockIdx.x * 256 + threadIdx.x;
    if (idx >= Bsz * Nsz * EMB) return;
    int e = idx % EMB;
    int bn = idx / EMB;
    int n = bn % Nsz, b = bn / Nsz;
    float v = 0.f;
    if (n > 0) {
        int lab = labels[b * Nsz + n - 1];
        v = table[(size_t)lab * EMB + e];
    }
    roA[(size_t)bn * KRO + HID + e] = v;
}

// ======== MFMA split-bf16 GEMM: C = A[M,K] @ W[Nc,K]^T + bias ========
template <int MODE>
__global__ __launch_bounds__(256) void mfma_gemm(const float* __restrict__ A,
                                                 const float* __restrict__ W,
                                                 const float* __restrict__ bias,
                                                 float* __restrict__ C,
                                                 int M, int Nc, int K, int ldC) {
    __shared__ unsigned short Ah[128][40], Al[128][40], Wh[128][40], Wl[128][40];
    int tid = threadIdx.x;
    int lane = tid & 63;
    int wave = tid >> 6;
    int wm = (wave >> 1) * 64, wn = (wave & 1) * 64;
    int m0 = blockIdx.y * 128, n0 = blockIdx.x * 128;
    int lrow = tid >> 1;
    int lcol = (tid & 1) * 16;
    bool aval = (m0 + lrow) < M;
    bool wval = (n0 + lrow) < Nc;
    const float* Arow = A + (size_t)(m0 + lrow) * K + lcol;
    const float* Wrow = W + (size_t)(n0 + lrow) * K + lcol;
    int frow = lane & 15, fk = (lane >> 4) * 8;

    f32x4 acc[4][4];
#pragma unroll
    for (int i = 0; i < 4; i++)
#pragma unroll
        for (int j = 0; j < 4; j++) acc[i][j] = (f32x4){0.f, 0.f, 0.f, 0.f};

    const float4 z4 = {0.f, 0.f, 0.f, 0.f};
    for (int k0 = 0; k0 < K; k0 += 32) {
#pragma unroll
        for (int c = 0; c < 16; c += 4) {
            float4 av = aval ? ld4(Arow + k0 + c) : z4;
            u16x4 hv, lv;
            hv.x = f2bf(av.x); lv.x = f2bf(av.x - bf2f(hv.x));
            hv.y = f2bf(av.y); lv.y = f2bf(av.y - bf2f(hv.y));
            hv.z = f2bf(av.z); lv.z = f2bf(av.z - bf2f(hv.z));
            hv.w = f2bf(av.w); lv.w = f2bf(av.w - bf2f(hv.w));
            *(u16x4*)&Ah[lrow][lcol + c] = hv;
            *(u16x4*)&Al[lrow][lcol + c] = lv;
            float4 wv = wval ? ld4(Wrow + k0 + c) : z4;
            hv.x = f2bf(wv.x); lv.x = f2bf(wv.x - bf2f(hv.x));
            hv.y = f2bf(wv.y); lv.y = f2bf(wv.y - bf2f(hv.y));
            hv.z = f2bf(wv.z); lv.z = f2bf(wv.z - bf2f(hv.z));
            hv.w = f2bf(wv.w); lv.w = f2bf(wv.w - bf2f(hv.w));
            *(u16x4*)&Wh[lrow][lcol + c] = hv;
            *(u16x4*)&Wl[lrow][lcol + c] = lv;
        }
        __syncthreads();
        s16x8 afh[4], afl[4], bfh[4], bfl[4];
#pragma unroll
        for (int i = 0; i < 4; i++) {
            afh[i] = *(const s16x8*)&Ah[wm + i * 16 + frow][fk];
            afl[i] = *(const s16x8*)&Al[wm + i * 16 + frow][fk];
            bfh[i] = *(const s16x8*)&Wh[wn + i * 16 + frow][fk];
            bfl[i] = *(const s16x8*)&Wl[wn + i * 16 + frow][fk];
        }
#pragma unroll
        for (int mi = 0; mi < 4; mi++)
#pragma unroll
            for (int ni = 0; ni < 4; ni++) {
                acc[mi][ni] = __builtin_amdgcn_mfma_f32_16x16x32_bf16(afh[mi], bfh[ni], acc[mi][ni], 0, 0, 0);
                acc[mi][ni] = __builtin_amdgcn_mfma_f32_16x16x32_bf16(afl[mi], bfh[ni], acc[mi][ni], 0, 0, 0);
                acc[mi][ni] = __builtin_amdgcn_mfma_f32_16x16x32_bf16(afh[mi], bfl[ni], acc[mi][ni], 0, 0, 0);
            }
        __syncthreads();
    }
    int crb = (lane >> 4) * 4;
    int ccol = lane & 15;
#pragma unroll
    for (int mi = 0; mi < 4; mi++) {
#pragma unroll
        for (int r = 0; r < 4; r++) {
            int m = m0 + wm + mi * 16 + crb + r;
#pragma unroll
            for (int ni = 0; ni < 4; ni++) {
                int n = n0 + wn + ni * 16 + ccol;
                if (MODE == 0) {
                    if (m < M && n < Nc) C[(size_t)m * ldC + n] = acc[mi][ni][r] + bias[n];
                } else {
                    float v = (n < Nc) ? acc[mi][ni][r] + bias[n] : -INFINITY;
                    float o = __shfl_xor(v, 1, 64);
                    if (((lane & 1) == 0) && m < M && n < Nc)
                        C[(size_t)m * ldC + (n >> 1)] = fmaxf(v, o);
                }
            }
        }
    }
}

// ---------------- inv_fertility ----------------
__global__ __launch_bounds__(256) void k_ifert(const float* __restrict__ enc,
                                               const float* __restrict__ Wfert,
                                               float* __restrict__ ifert) {
    int wv = (blockIdx.x * 256 + threadIdx.x) >> 6;
    int lane = threadIdx.x & 63;
    if (wv >= Bsz * Tsz) return;
    const float* row = enc + (size_t)wv * ENC;
    float s = 0.f;
    for (int k = lane * 4; k < ENC; k += 256) s += dot4(ld4(row + k), ld4(Wfert + k));
    for (int o = 32; o; o >>= 1) s += __shfl_xor(s, o, 64);
    if (lane == 0) ifert[wv] = 1.f / (1.f + __expf(-s));
}

// ---------------- grid barrier: NO cache maintenance; explicit vmcnt drain ----------------
// bar (uints): [g<<4] g<32: arrival groups; [512]: root; [1024+(w<<4)] w<64: wake lines.
// Requires gridDim.x % 64 == 0. Monotonic counters, zeroed by k_init.
// CRITICAL (R2 lesson): each wave drains vmcnt(0) BEFORE the arrival bump, so all coherent
// stores/atomics of the phase are at the LLC before any consumer can pass the barrier.
// Wake is fanned out over 64 lines to avoid single-line poll congestion (R1/R4 lesson).
__device__ __forceinline__ void gsync(unsigned* bm, unsigned& ep) {
    asm volatile("s_waitcnt vmcnt(0)" ::: "memory");  // per-wave drain of coherent stores/atomics
    __syncthreads();
    if (threadIdx.x == 0) {
        ep++;
        unsigned gsize = gridDim.x >> 5;
        unsigned grp = blockIdx.x & 31;
        unsigned wln = blockIdx.x & 63;
        unsigned r = __hip_atomic_fetch_add(&bm[grp << 4], 1u,
                                            __ATOMIC_RELAXED, __HIP_MEMORY_SCOPE_AGENT) + 1u;
        if (r == ep * gsize) {
            unsigned rr = __hip_atomic_fetch_add(&bm[512], 1u,
                                                 __ATOMIC_RELAXED, __HIP_MEMORY_SCOPE_AGENT) + 1u;
            if (rr == (ep << 5)) {
#pragma unroll
                for (int w = 0; w < 64; w++)
                    __hip_atomic_store(&bm[1024 + (w << 4)], ep,
                                       __ATOMIC_RELAXED, __HIP_MEMORY_SCOPE_AGENT);
            }
        }
        while (__hip_atomic_load(&bm[1024 + (wln << 4)], __ATOMIC_RELAXED,
                                 __HIP_MEMORY_SCOPE_AGENT) < ep)
            __builtin_amdgcn_s_sleep(8);
        asm volatile("" ::: "memory");
    }
    __syncthreads();
}

// ---------------- persistent decode loop ----------------
// R4's proven dataflow; coherence via LLC ops instead of fences:
//   mutable cross-block (hbuf, st, expw, denom, accum, roA-ctx reads) -> ldcg/stcg/atomicAdd
//   immutable streams (weights, encctx, enc, emb, ifert) -> plain cached loads (L2 stays warm)
// Phase A: gates+cell -> hcur (stcg) + roA h-col (plain, post-loop only); zero denom
// Phase B: s_t = h @ Ws^T -> st (stcg)
// Phase C: energies -> expw = exp(e) (|e| <= sum|v_att| ~16, max-free safe; proven R4),
//          atomicAdd denom
// Phase D: ctx = sum_t (expw/denom)*enc -> atomicAdd into roA; accum += expw*ifert*0.5/denom
__global__ __launch_bounds__(256) void k_loop(
    const float* __restrict__ enc, const int* __restrict__ seqlen,
    const float* __restrict__ Wih, const float* __restrict__ Whh,
    const float* __restrict__ bih, const float* __restrict__ bhh,
    const float* __restrict__ Wsm, const float* __restrict__ Wfb,
    const float* __restrict__ vatt, const float* __restrict__ ifert,
    float* roA, float* __restrict__ cbuf, const float* __restrict__ encctx,
    float* __restrict__ accum, float* __restrict__ expw, float* __restrict__ st,
    float* __restrict__ denom, float* __restrict__ hbuf, unsigned* __restrict__ bar) {
    const int tid = threadIdx.x;
    const int lane = tid & 63;
    const int wid4 = (blockIdx.x << 2) + (tid >> 6);
    const int nwv = gridDim.x << 2;
    const int gtid = blockIdx.x * 256 + tid;
    const int gth = gridDim.x * 256;
    unsigned ep = 0;

    for (int t = 0; t < Nsz; ++t) {
        const int cur = t & 1, prev = cur ^ 1;
        float* hcur = hbuf + cur * (Bsz * HID);
        const float* hprev = hbuf + prev * (Bsz * HID);

        // ---------------- Phase A: gates + LSTM cell ----------------
        if (gtid < Bsz) stcg(&denom[gtid * 16], 0.f);        // this step's denom slot
        for (int it = wid4; it < 2 * HID; it += nwv) {
            int j = it >> 1;
            int b0 = (it & 1) << 3;
            float acc[4][8];
#pragma unroll
            for (int g = 0; g < 4; g++)
#pragma unroll
                for (int bb = 0; bb < 8; bb++) acc[g][bb] = 0.f;

            const float* wi0 = Wih + (size_t)(0 * HID + j) * KX;
            const float* wi1 = Wih + (size_t)(1 * HID + j) * KX;
            const float* wi2 = Wih + (size_t)(2 * HID + j) * KX;
            const float* wi3 = Wih + (size_t)(3 * HID + j) * KX;
            for (int k = lane * 4; k < EMB; k += 256) {
                float4 w0 = ld4(wi0 + k), w1 = ld4(wi1 + k), w2 = ld4(wi2 + k), w3 = ld4(wi3 + k);
#pragma unroll
                for (int bb = 0; bb < 8; bb++) {
                    float4 x = ld4(roA + (size_t)((b0 + bb) * Nsz + t) * KRO + HID + k);  // emb: immutable
                    acc[0][bb] += dot4(w0, x); acc[1][bb] += dot4(w1, x);
                    acc[2][bb] += dot4(w2, x); acc[3][bb] += dot4(w3, x);
                }
            }
            if (t > 0) {
                for (int k = lane * 4; k < ENC; k += 256) {
                    float4 w0 = ld4(wi0 + EMB + k), w1 = ld4(wi1 + EMB + k);
                    float4 w2 = ld4(wi2 + EMB + k), w3 = ld4(wi3 + EMB + k);
#pragma unroll
                    for (int bb = 0; bb < 8; bb++) {
                        float4 x = ld4cg(roA + (size_t)((b0 + bb) * Nsz + (t - 1)) * KRO + HID + EMB + k);
                        acc[0][bb] += dot4(w0, x); acc[1][bb] += dot4(w1, x);
                        acc[2][bb] += dot4(w2, x); acc[3][bb] += dot4(w3, x);
                    }
                }
                const float* wh0 = Whh + (size_t)(0 * HID + j) * HID;
                const float* wh1 = Whh + (size_t)(1 * HID + j) * HID;
                const float* wh2 = Whh + (size_t)(2 * HID + j) * HID;
                const float* wh3 = Whh + (size_t)(3 * HID + j) * HID;
                for (int k = lane * 4; k < HID; k += 256) {
                    float4 w0 = ld4(wh0 + k), w1 = ld4(wh1 + k), w2 = ld4(wh2 + k), w3 = ld4(wh3 + k);
#pragma unroll
                    for (int bb = 0; bb < 8; bb++) {
                        float4 x = ld4cg(hprev + (b0 + bb) * HID + k);
                        acc[0][bb] += dot4(w0, x); acc[1][bb] += dot4(w1, x);
                        acc[2][bb] += dot4(w2, x); acc[3][bb] += dot4(w3, x);
                    }
                }
            }
#pragma unroll
            for (int g = 0; g < 4; g++)
#pragma unroll
                for (int bb = 0; bb < 8; bb++) {
                    float v = acc[g][bb];
                    for (int o = 32; o; o >>= 1) v += __shfl_xor(v, o, 64);
                    acc[g][bb] = v;
                }
            if (lane < 8) {
                int b = b0 + lane;
                float gi = 0.f, gf = 0.f, gg = 0.f, go = 0.f;
#pragma unroll
                for (int bb = 0; bb < 8; bb++)
                    if (lane == bb) { gi = acc[0][bb]; gf = acc[1][bb]; gg = acc[2][bb]; go = acc[3][bb]; }
                gi += bih[j] + bhh[j];
                gf += bih[HID + j] + bhh[HID + j];
                gg += bih[2 * HID + j] + bhh[2 * HID + j];
                go += bih[3 * HID + j] + bhh[3 * HID + j];
                float cold = (t > 0) ? cbuf[b * HID + j] : 0.f;   // same-wave private across steps
                float cn = sigmoidf_(gf) * cold + sigmoidf_(gi) * ftanh_(gg);
                float hn = sigmoidf_(go) * ftanh_(cn);
                cbuf[b * HID + j] = cn;
                roA[(size_t)(b * Nsz + t) * KRO + j] = hn;   // plain: read post-loop by GEMM only
                stcg(&hcur[b * HID + j], hn);                // coherent: read by B / next A
            }
        }
        gsync(bar, ep);

        // ---------------- Phase B: s_t, one wave per (b, 16-unit group) ----------------
        for (int it = wid4; it < 1024; it += nwv) {
            int b = it >> 6, agrp = it & 63;
            const float* hb = hcur + b * HID + lane * 4;
            float4 h0 = ld4cg(hb), h1 = ld4cg(hb + 256), h2 = ld4cg(hb + 512), h3 = ld4cg(hb + 768);
            float acc2[16];
#pragma unroll
            for (int ai = 0; ai < 16; ai++) {
                const float* wr = Wsm + (size_t)(agrp * 16 + ai) * HID + lane * 4;
                acc2[ai] = dot4(h0, ld4(wr)) + dot4(h1, ld4(wr + 256))
                         + dot4(h2, ld4(wr + 512)) + dot4(h3, ld4(wr + 768));
            }
#pragma unroll
            for (int ai = 0; ai < 16; ai++) {
                float v = acc2[ai];
                for (int o = 32; o; o >>= 1) v += __shfl_xor(v, o, 64);
                acc2[ai] = v;
            }
            if (lane < 16) {
                float v = 0.f;
#pragma unroll
                for (int ai = 0; ai < 16; ai++)
                    if (lane == ai) v = acc2[ai];
                stcg(&st[b * ATT + agrp * 16 + lane], v);
            }
        }
        gsync(bar, ep);

        // ---------------- Phase C: energies -> exp weights + denominators ----------------
        for (int it = wid4; it < Bsz * 250; it += nwv) {
            int b = it / 250;
            int tt0 = (it - b * 250) << 2;
            int L = seqlen[b];
            float w0 = 0.f, w1 = 0.f, w2 = 0.f, w3 = 0.f;
            if (tt0 < L) {
                const float* sr = st + b * ATT;
                const float* ecb = encctx + ((size_t)b * Tsz + tt0) * ATT;
                float ac0 = ldcg(&accum[b * Tsz + tt0 + 0]);
                float ac1 = ldcg(&accum[b * Tsz + tt0 + 1]);
                float ac2 = ldcg(&accum[b * Tsz + tt0 + 2]);
                float ac3 = ldcg(&accum[b * Tsz + tt0 + 3]);
                float e0 = 0.f, e1 = 0.f, e2 = 0.f, e3 = 0.f;
                for (int k = lane * 4; k < ATT; k += 256) {
                    float4 s4 = ld4cg(sr + k);
                    float4 f4 = ld4(Wfb + k), v4 = ld4(vatt + k);
                    float4 c0 = ld4(ecb + k);
                    float4 c1 = ld4(ecb + ATT + k);
                    float4 c2 = ld4(ecb + 2 * ATT + k);
                    float4 c3 = ld4(ecb + 3 * ATT + k);
                    e0 += ftanh_(c0.x + s4.x + ac0 * f4.x) * v4.x + ftanh_(c0.y + s4.y + ac0 * f4.y) * v4.y
                        + ftanh_(c0.z + s4.z + ac0 * f4.z) * v4.z + ftanh_(c0.w + s4.w + ac0 * f4.w) * v4.w;
                    e1 += ftanh_(c1.x + s4.x + ac1 * f4.x) * v4.x + ftanh_(c1.y + s4.y + ac1 * f4.y) * v4.y
                        + ftanh_(c1.z + s4.z + ac1 * f4.z) * v4.z + ftanh_(c1.w + s4.w + ac1 * f4.w) * v4.w;
                    e2 += ftanh_(c2.x + s4.x + ac2 * f4.x) * v4.x + ftanh_(c2.y + s4.y + ac2 * f4.y) * v4.y
                        + ftanh_(c2.z + s4.z + ac2 * f4.z) * v4.z + ftanh_(c2.w + s4.w + ac2 * f4.w) * v4.w;
                    e3 += ftanh_(c3.x + s4.x + ac3 * f4.x) * v4.x + ftanh_(c3.y + s4.y + ac3 * f4.y) * v4.y
                        + ftanh_(c3.z + s4.z + ac3 * f4.z) * v4.z + ftanh_(c3.w + s4.w + ac3 * f4.w) * v4.w;
                }
                for (int o = 32; o; o >>= 1) {
                    e0 += __shfl_xor(e0, o, 64);
                    e1 += __shfl_xor(e1, o, 64);
                    e2 += __shfl_xor(e2, o, 64);
                    e3 += __shfl_xor(e3, o, 64);
                }
                w0 = __expf(e0);
                w1 = (tt0 + 1 < L) ? __expf(e1) : 0.f;
                w2 = (tt0 + 2 < L) ? __expf(e2) : 0.f;
                w3 = (tt0 + 3 < L) ? __expf(e3) : 0.f;
            }
            if (lane == 0) {
                float* wp = expw + b * Tsz + tt0;
                stcg(wp + 0, w0); stcg(wp + 1, w1); stcg(wp + 2, w2); stcg(wp + 3, w3);
                float wsum = w0 + w1 + w2 + w3;
                if (wsum > 0.f) atomicAdd(&denom[b * 16], wsum);
            }
        }
        gsync(bar, ep);

        // ---------------- Phase D: context + accum update ----------------
        for (int it = wid4; it < 1024; it += nwv) {
            int b = it >> 6;
            int ch = (it >> 1) & 31;
            int half = it & 1;
            int L = seqlen[b];
            int tt0 = ch * 32;
            int tt1 = min(tt0 + 32, L);
            if (tt0 < tt1) {
                float inv = 1.f / ldcg(&denom[b * 16]);
                int d = (half << 8) + lane * 4;
                const float* ebase = enc + (size_t)b * Tsz * ENC + d;
                const float* wrow = expw + b * Tsz;
                float s0 = 0.f, s1 = 0.f, s2 = 0.f, s3 = 0.f;
                for (int tt = tt0; tt < tt1; ++tt) {
                    float wt = ldcg(wrow + tt);
                    float4 e4 = ld4(ebase + (size_t)tt * ENC);
                    s0 += wt * e4.x; s1 += wt * e4.y; s2 += wt * e4.z; s3 += wt * e4.w;
                }
                float* dst = roA + (size_t)(b * Nsz + t) * KRO + HID + EMB + d;
                atomicAdd(dst + 0, s0 * inv);
                atomicAdd(dst + 1, s1 * inv);
                atomicAdd(dst + 2, s2 * inv);
                atomicAdd(dst + 3, s3 * inv);
            }
        }
        for (int i = gtid; i < Bsz * Tsz; i += gth) {
            int b = i / Tsz;
            float a = ldcg(&accum[i]);
            stcg(&accum[i], a + ldcg(&expw[i]) * ifert[i] * (0.5f / ldcg(&denom[b * 16])));
        }
        gsync(bar, ep);
    }
}

// ---------------- final small outputs: h, c, att_ctx, accum ----------------
__global__ __launch_bounds__(256) void k_final(const float* __restrict__ roA, const float* __restrict__ cbuf,
                                               const float* __restrict__ accum, float* __restrict__ out) {
    int idx = blockIdx.x * 256 + threadIdx.x;
    const int base = Bsz * Nsz * VOCAB;
    const int OH = Bsz * HID, OC = Bsz * HID, OA = Bsz * ENC, OAC = Bsz * Tsz;
    if (idx < OH) {
        int b = idx / HID, j = idx % HID;
        out[base + idx] = roA[(size_t)(b * Nsz + Nsz - 1) * KRO + j];
        return;
    }
    idx -= OH;
    if (idx < OC) { out[base + OH + idx] = cbuf[idx]; return; }
    idx -= OC;
    if (idx < OA) {
        int b = idx / ENC, d = idx % ENC;
        out[base + OH + OC + idx] = roA[(size_t)(b * Nsz + Nsz - 1) * KRO + HID + EMB + d];
        return;
    }
    idx -= OA;
    if (idx < OAC) out[base + OH + OC + OA + idx] = accum[idx];
}

extern "C" void kernel_launch(void* const* d_in, const int* in_sizes, int n_in,
                              void* d_out, int out_size, void* d_ws, size_t ws_size,
                              hipStream_t stream) {
    const float* enc   = (const float*)d_in[0];
    const int* labels  = (const int*)d_in[1];
    const int* seqlen  = (const int*)d_in[2];
    const float* table = (const float*)d_in[3];
    const float* Wih   = (const float*)d_in[4];
    const float* Whh   = (const float*)d_in[5];
    const float* bih   = (const float*)d_in[6];
    const float* bhh   = (const float*)d_in[7];
    const float* Wsm   = (const float*)d_in[8];
    const float* Wenc  = (const float*)d_in[9];
    const float* benc  = (const float*)d_in[10];
    const float* vatt  = (const float*)d_in[11];
    const float* Wfert = (const float*)d_in[12];
    const float* Wfb   = (const float*)d_in[13];
    const float* Wro   = (const float*)d_in[14];
    const float* bro   = (const float*)d_in[15];
    const float* Wout  = (const float*)d_in[16];
    const float* bout  = (const float*)d_in[17];
    float* out = (float*)d_out;

    // workspace layout (floats); ~83 MB. denom/bar/hbuf alias the FRONT of rmx
    // (rmx only written by the post-loop readout GEMM).
    float* ws = (float*)d_ws;
    float* roA    = ws;                              // [B*N][KRO]
    float* cbuf   = roA + (size_t)1600 * KRO;        // B*HID
    float* encctx = cbuf + Bsz * HID;                // [B*T][ATT]
    float* ifert  = encctx + (size_t)Bsz * Tsz * ATT;
    float* accum  = ifert + Bsz * Tsz;
    float* enw    = accum + Bsz * Tsz;               // exp-weights
    float* st     = enw + Bsz * Tsz;
    float* rmx    = st + Bsz * ATT;                  // [B*N][512]
    float* denomF = rmx;                             // [b*16], one slot per batch (floats 0..256)
    unsigned* barU = (unsigned*)(rmx + 512);         // barrier counters (uints 0..2048 -> floats 512..2560)
    float* hbuf   = rmx + 4096;                      // [2][B*HID]

    k_init<<<3200, 256, 0, stream>>>(accum, roA, rmx);
    k_embed<<<(Bsz * Nsz * EMB + 255) / 256, 256, 0, stream>>>(labels, table, roA);
    mfma_gemm<0><<<dim3(ATT / 128, (Bsz * Tsz) / 128), 256, 0, stream>>>(enc, Wenc, benc, encctx,
                                                                        Bsz * Tsz, ATT, ENC, ATT);
    k_ifert<<<(Bsz * Tsz * 64 + 255) / 256, 256, 0, stream>>>(enc, Wfert, ifert);

    // persistent decode loop: grid clamped to guaranteed co-residency
    static int s_nblk = 0;
    if (s_nblk == 0) {
        int occ = 0;
        if (hipOccupancyMaxActiveBlocksPerMultiprocessor(&occ, k_loop, 256, 0) != hipSuccess || occ < 1)
            occ = 1;
        long cap = (long)occ * 256;   // 256 CUs on MI355X
        s_nblk = (int)(cap < 1536 ? cap : 1536);
        s_nblk &= ~63;                // barrier requires multiple of 64 (wake lines)
        if (s_nblk < 64) s_nblk = 64;
    }
    k_loop<<<s_nblk, 256, 0, stream>>>(enc, seqlen, Wih, Whh, bih, bhh, Wsm, Wfb, vatt,
                                       ifert, roA, cbuf, encctx, accum, enw, st, denomF, hbuf, barU);

    // readout: [1600,2176]@[2176,1024] + bias -> maxout -> rmx [1600,512]
    mfma_gemm<1><<<dim3(1024 / 128, (1600 + 127) / 128), 256, 0, stream>>>(roA, Wro, bro, rmx,
                                                                          1600, 1024, KRO, 512);
    // logits: [1600,512]@[512,10025] + bias -> d_out
    mfma_gemm<0><<<dim3((VOCAB + 127) / 128, (1600 + 127) / 128), 256, 0, stream>>>(rmx, Wout, bout, out,
                                                                                   1600, VOCAB, 512, VOCAB);
    k_final<<<(Bsz * HID * 2 + Bsz * ENC + Bsz * Tsz + 255) / 256, 256, 0, stream>>>(roA, cbuf, accum, out);
}